// Round 5
// baseline (261.506 us; speedup 1.0000x reference)
//
#include <hip/hip_runtime.h>

// PatchAttentionLayer, restructured:
//   G_b = x_b x_b^T (Gram, bf16 MFMA, upper tiles + mirror), s_b = x_b 1
//   BN stats analytic (quadratic form on Ghat); Wp = diag(a)W, cvec.
//   Z = Wk'^T Wq'; F_b = G_b Z; T_b = Wv' F_b + rank-1; out = T_b x_b + off 1^T.
// R5: mid1 split into mid_a/mid_b/mid_c with fully-coalesced matvec orientations
// (fp32 transposes WkTf/WvTf; G symmetry for gy); mirror via LDS-tile transpose.

#define BB 8
#define CC 256
#define NPIX 4096
#define PTOT 32768
#define EPSV 1e-5f
#define SCALEV 0.125f

// ---- workspace layout (float offsets; ushort buffers = count/2 floats) ----
#define OFF_G     0L          // 524288
#define OFF_S     524288L     // 2048
#define OFF_GHAT  526336L     // 65536
#define OFF_XBAR  591872L     // 256
#define OFF_WP    592128L     // 196608
#define OFF_WKTF  788736L     // 65536
#define OFF_WVTF  854272L     // 65536
#define OFF_CVEC  919808L     // 768
#define OFF_U     920576L     // 2048
#define OFF_W2    922624L     // 2048
#define OFF_HB    924672L     // 2048
#define OFF_GY    926720L     // 2048
#define OFF_Y     928768L     // 256
#define OFF_R     929024L     // 256
#define OFF_OFFV  929280L     // 2048
#define OFF_GBF   931328L     // 8*65536 ushort = 262144 floats
#define OFF_WQT   1193472L    // 65536 ushort = 32768 floats
#define OFF_WKT   1226240L    // 32768
#define OFF_WVB   1259008L    // 32768
#define OFF_ZT    1291776L    // 32768
#define OFF_FT    1324544L    // 262144
#define OFF_TBF   1586688L    // 262144
// total 1848832 floats = 7.40 MB

typedef __attribute__((ext_vector_type(8))) short short8;
typedef __attribute__((ext_vector_type(4))) float f32x4;

#define MFMA16(a, b, c) __builtin_amdgcn_mfma_f32_16x16x32_bf16((a), (b), (c), 0, 0, 0)

__device__ __forceinline__ ushort f2bf(float f) {
    union { float f; unsigned u; } v; v.f = f;
    const unsigned r = (v.u + 0x7FFFu + ((v.u >> 16) & 1u)) >> 16;
    return (ushort)r;
}

__device__ __forceinline__ float block_reduce(float v, float* red, int tid) {
    red[tid] = v; __syncthreads();
    for (int st = 128; st > 0; st >>= 1) {
        if (tid < st) red[tid] += red[tid + st];
        __syncthreads();
    }
    float r = red[0]; __syncthreads();
    return r;
}

// ---- Gram via MFMA: 64x64 upper-triangle tiles, ks=8 K-split, rowsum fused ----
// grid (8 ks, 8 b, 10 tiles)
__global__ __launch_bounds__(256) void gram_mfma(const float* __restrict__ x,
                                                 float* __restrict__ G,
                                                 float* __restrict__ S) {
    __shared__ __align__(16) ushort Ab[64 * 72];
    __shared__ __align__(16) ushort Bb[64 * 72];
    __shared__ float rs[64];
    const int tid = threadIdx.x;
    const int ks = blockIdx.x, b = blockIdx.y, tt = blockIdx.z;
    const int itA[10] = {0,0,0,0,1,1,1,2,2,3};
    const int jtA[10] = {0,1,2,3,1,2,3,2,3,3};
    const int it = itA[tt], jt = jtA[tt];
    const bool diag = (it == jt);
    const int i0 = it * 64, j0 = jt * 64, k0 = ks * 512;
    const float* xb = x + (long)b * CC * NPIX;
    const int c = tid & 15, rp = tid >> 4;
    const int wave = tid >> 6, lane = tid & 63;
    const int wr = (wave >> 1) * 32, wc = (wave & 1) * 32;
    const int m = lane & 15, q8 = (lane >> 4) * 8;

    if (tid < 64) rs[tid] = 0.f;
    float rloc[4] = {0.f, 0.f, 0.f, 0.f};
    f32x4 acc[2][2];
    #pragma unroll
    for (int a = 0; a < 2; ++a)
        #pragma unroll
        for (int q = 0; q < 2; ++q) acc[a][q] = (f32x4){0.f, 0.f, 0.f, 0.f};

    for (int kc = 0; kc < 512; kc += 64) {
        __syncthreads();
        #pragma unroll
        for (int pp = 0; pp < 4; ++pp) {
            const int row = pp * 16 + rp;
            const float4 v = *(const float4*)&xb[(long)(i0 + row) * NPIX + k0 + kc + c * 4];
            rloc[pp] += v.x + v.y + v.z + v.w;
            ushort4 w;
            w.x = f2bf(v.x); w.y = f2bf(v.y); w.z = f2bf(v.z); w.w = f2bf(v.w);
            *(ushort4*)&Ab[row * 72 + c * 4] = w;
        }
        if (!diag) {
            #pragma unroll
            for (int pp = 0; pp < 4; ++pp) {
                const int row = pp * 16 + rp;
                const float4 v = *(const float4*)&xb[(long)(j0 + row) * NPIX + k0 + kc + c * 4];
                ushort4 w;
                w.x = f2bf(v.x); w.y = f2bf(v.y); w.z = f2bf(v.z); w.w = f2bf(v.w);
                *(ushort4*)&Bb[row * 72 + c * 4] = w;
            }
        }
        __syncthreads();
        const ushort* Bsrc = diag ? Ab : Bb;
        #pragma unroll
        for (int kk = 0; kk < 2; ++kk) {
            short8 af[2], bfv[2];
            #pragma unroll
            for (int a = 0; a < 2; ++a)
                af[a] = *(const short8*)&Ab[(wr + a * 16 + m) * 72 + kk * 32 + q8];
            #pragma unroll
            for (int q = 0; q < 2; ++q)
                bfv[q] = *(const short8*)&Bsrc[(wc + q * 16 + m) * 72 + kk * 32 + q8];
            #pragma unroll
            for (int a = 0; a < 2; ++a)
                #pragma unroll
                for (int q = 0; q < 2; ++q)
                    acc[a][q] = MFMA16(af[a], bfv[q], acc[a][q]);
        }
    }
    if (diag) {
        #pragma unroll
        for (int pp = 0; pp < 4; ++pp) atomicAdd(&rs[pp * 16 + rp], rloc[pp]);
        __syncthreads();
        if (tid < 64) atomicAdd(&S[b * CC + i0 + tid], rs[tid]);
    }
    float* Gb = G + (long)b * 65536;
    const int rq = (lane >> 4) * 4;
    #pragma unroll
    for (int a = 0; a < 2; ++a) {
        #pragma unroll
        for (int q = 0; q < 2; ++q) {
            const int gj = j0 + wc + q * 16 + m;
            #pragma unroll
            for (int reg = 0; reg < 4; ++reg)
                atomicAdd(&Gb[(long)(i0 + wr + a * 16 + rq + reg) * 256 + gj], acc[a][q][reg]);
        }
    }
}

// ---- mirror via LDS-tile transpose; Gbf; Ghat; xbar. grid 17 blocks ----
__global__ __launch_bounds__(256) void mirror_t(float* __restrict__ G,
                                                const float* __restrict__ S,
                                                float* __restrict__ Ghat,
                                                float* __restrict__ xbar,
                                                ushort* __restrict__ Gbf) {
    const int blk = blockIdx.x, tid = threadIdx.x;
    if (blk == 16) {
        float sum = 0.f;
        for (int b = 0; b < BB; ++b) sum += S[b * CC + tid];
        xbar[tid] = sum * (1.0f / PTOT);
        return;
    }
    const int ti = blk >> 2, tj = blk & 3;
    const int r = tid >> 2, c4 = (tid & 3) * 16;
    float gacc[16] = {};
    if (ti <= tj) {
        const long rowbase = (long)(ti * 64 + r) * 256 + tj * 64 + c4;
        for (int b = 0; b < BB; ++b) {
            const float* Gb = G + (long)b * 65536;
            ushort* Qb = Gbf + (long)b * 65536;
            #pragma unroll
            for (int k = 0; k < 4; ++k) {
                const float4 v = *(const float4*)&Gb[rowbase + k * 4];
                ushort4 w;
                w.x = f2bf(v.x); w.y = f2bf(v.y); w.z = f2bf(v.z); w.w = f2bf(v.w);
                *(ushort4*)&Qb[rowbase + k * 4] = w;
                gacc[k * 4 + 0] += v.x; gacc[k * 4 + 1] += v.y;
                gacc[k * 4 + 2] += v.z; gacc[k * 4 + 3] += v.w;
            }
        }
        #pragma unroll
        for (int k = 0; k < 16; ++k) Ghat[rowbase + k] = gacc[k] * (1.0f / PTOT);
    } else {
        __shared__ float tile[64 * 68];
        const long srcbase = (long)(tj * 64 + r) * 256 + ti * 64 + c4;
        const long dstbase = (long)(ti * 64 + r) * 256 + tj * 64 + c4;
        for (int b = 0; b < BB; ++b) {
            float* Gb = G + (long)b * 65536;
            ushort* Qb = Gbf + (long)b * 65536;
            #pragma unroll
            for (int k = 0; k < 4; ++k)
                *(float4*)&tile[r * 68 + c4 + k * 4] = *(const float4*)&Gb[srcbase + k * 4];
            __syncthreads();
            #pragma unroll
            for (int k = 0; k < 4; ++k) {
                float4 v;
                v.x = tile[(c4 + k * 4 + 0) * 68 + r];
                v.y = tile[(c4 + k * 4 + 1) * 68 + r];
                v.z = tile[(c4 + k * 4 + 2) * 68 + r];
                v.w = tile[(c4 + k * 4 + 3) * 68 + r];
                *(float4*)&Gb[dstbase + k * 4] = v;
                ushort4 w;
                w.x = f2bf(v.x); w.y = f2bf(v.y); w.z = f2bf(v.z); w.w = f2bf(v.w);
                *(ushort4*)&Qb[dstbase + k * 4] = w;
                gacc[k * 4 + 0] += v.x; gacc[k * 4 + 1] += v.y;
                gacc[k * 4 + 2] += v.z; gacc[k * 4 + 3] += v.w;
            }
            __syncthreads();
        }
        #pragma unroll
        for (int k = 0; k < 16; ++k) Ghat[dstbase + k] = gacc[k] * (1.0f / PTOT);
    }
}

// ---- BN stats; writes fp32 Wp (+ fp32 transposes of Wk',Wv'), bf16 mats, cvec ----
__global__ void stats_quad(const float* __restrict__ Wq, const float* __restrict__ Wk,
                           const float* __restrict__ Wv, const float* __restrict__ Ghat,
                           const float* __restrict__ xbar,
                           const float* bq, const float* gq, const float* betaq,
                           const float* bk, const float* gk, const float* betak,
                           const float* bv, const float* gv, const float* betav,
                           float* __restrict__ Wp, float* __restrict__ cvec,
                           ushort* __restrict__ WqT, ushort* __restrict__ WkT,
                           ushort* __restrict__ Wvb, float* __restrict__ WkTf,
                           float* __restrict__ WvTf) {
    const int o = blockIdx.x, t = blockIdx.y, tid = threadIdx.x;
    const float* Wt  = t == 0 ? Wq : (t == 1 ? Wk : Wv);
    const float* bt  = t == 0 ? bq : (t == 1 ? bk : bv);
    const float* gt  = t == 0 ? gq : (t == 1 ? gk : gv);
    const float* bet = t == 0 ? betaq : (t == 1 ? betak : betav);
    __shared__ float wrow[256];
    __shared__ float red[256];
    wrow[tid] = Wt[o * 256 + tid];
    __syncthreads();
    const float* grow = Ghat + (long)tid * 256;
    float tj = 0.f;
    #pragma unroll 8
    for (int k = 0; k < 256; k += 4) {
        const float4 g = *(const float4*)&grow[k];
        tj += g.x * wrow[k] + g.y * wrow[k + 1] + g.z * wrow[k + 2] + g.w * wrow[k + 3];
    }
    const float q2 = block_reduce(wrow[tid] * tj, red, tid);
    const float wx = block_reduce(wrow[tid] * xbar[tid], red, tid);
    const float bo = bt[o];
    const float mu = wx + bo;
    const float var = q2 + 2.f * bo * mu - bo * bo - mu * mu;
    const float a = gt[o] * rsqrtf(var + EPSV);
    const float wpv = a * wrow[tid];
    Wp[(long)t * 65536 + o * 256 + tid] = wpv;
    const ushort wb = f2bf(wpv);
    if (t == 0) {
        WqT[(long)tid * 256 + o] = wb;
    } else if (t == 1) {
        WkT[(long)tid * 256 + o] = wb;
        WkTf[(long)tid * 256 + o] = wpv;
    } else {
        Wvb[(long)o * 256 + tid] = wb;
        WvTf[(long)tid * 256 + o] = wpv;
    }
    if (tid == 0) cvec[t * 256 + o] = a * (bo - mu) + bet[o];
}

// ---- mid_a: u_b = Wv' s_b, w_b = Wk' s_b (blocks 0-7); y, r (block 8) ----
__global__ __launch_bounds__(256) void mid_a(const float* __restrict__ Wp,
                                             const float* __restrict__ WkTf,
                                             const float* __restrict__ WvTf,
                                             const float* __restrict__ S,
                                             const float* __restrict__ cvec,
                                             float* __restrict__ u, float* __restrict__ w,
                                             float* __restrict__ y, float* __restrict__ r) {
    const int bidx = blockIdx.x, tid = threadIdx.x;
    if (bidx < 8) {
        __shared__ float sh[256];
        sh[tid] = S[bidx * 256 + tid]; __syncthreads();
        float uu = 0.f, ww = 0.f;
        #pragma unroll 8
        for (int j = 0; j < 256; ++j) {
            uu += WvTf[(long)j * 256 + tid] * sh[j];
            ww += WkTf[(long)j * 256 + tid] * sh[j];
        }
        u[bidx * 256 + tid] = uu;
        w[bidx * 256 + tid] = ww;
    } else {
        __shared__ float cqs[256], cks[256];
        cqs[tid] = cvec[tid]; cks[tid] = cvec[256 + tid]; __syncthreads();
        float yy = 0.f, rr = 0.f;
        #pragma unroll 8
        for (int o = 0; o < 256; ++o) {
            yy += Wp[65536L + (long)o * 256 + tid] * cqs[o];
            rr += Wp[(long)o * 256 + tid] * cks[o];
        }
        y[tid] = yy;
        r[tid] = rr;
    }
}

// ---- mid_b: h_b = Wq'^T w_b ; gy_b = G_b y (G symmetric -> coalesced) ----
__global__ __launch_bounds__(256) void mid_b(const float* __restrict__ Wp,
                                             const float* __restrict__ G,
                                             const float* __restrict__ w,
                                             const float* __restrict__ y,
                                             float* __restrict__ hb,
                                             float* __restrict__ gy) {
    const int b = blockIdx.x, tid = threadIdx.x;
    __shared__ float wl[256], yl[256];
    wl[tid] = w[b * 256 + tid]; yl[tid] = y[tid]; __syncthreads();
    float hh = 0.f, gg = 0.f;
    #pragma unroll 8
    for (int o = 0; o < 256; ++o) {
        hh += Wp[(long)o * 256 + tid] * wl[o];
        gg += G[(long)b * 65536 + (long)o * 256 + tid] * yl[o];
    }
    hb[b * 256 + tid] = hh;
    gy[b * 256 + tid] = gg;
}

// ---- mid_c: vg_b = Wv' gy_b ; reduces ; offv ----
__global__ __launch_bounds__(256) void mid_c(const float* __restrict__ WvTf,
                                             const float* __restrict__ gy,
                                             const float* __restrict__ u,
                                             const float* __restrict__ w,
                                             const float* __restrict__ cvec,
                                             float* __restrict__ offv) {
    const int b = blockIdx.x, tid = threadIdx.x;
    __shared__ float gyl[256], red[256], cqs[256], cks[256];
    gyl[tid] = gy[b * 256 + tid];
    cqs[tid] = cvec[tid];
    cks[tid] = cvec[256 + tid];
    const float cv = cvec[512 + tid];
    const float uu = u[b * 256 + tid];
    const float ww = w[b * 256 + tid];
    __syncthreads();
    float vg = 0.f;
    #pragma unroll 8
    for (int j = 0; j < 256; ++j) vg += WvTf[(long)j * 256 + tid] * gyl[j];
    const float dkq = block_reduce(cqs[tid] * cks[tid], red, tid);
    const float dwq = block_reduce(ww * cqs[tid], red, tid);
    offv[b * 256 + tid] = SCALEV * (vg + uu * dkq + cv * (dwq + 4096.0f * dkq));
}

// ---- bf16 MFMA 128x128-tile GEMM, K=256, fragments direct from L2 ----
// mode 0: store D^T plain bf16.  mode 1: rank-1 epilogue + scale, row-major.
__global__ __launch_bounds__(256) void gemm_mid(const ushort* __restrict__ A, long sA,
                                                const ushort* __restrict__ B, long sB,
                                                ushort* __restrict__ D, long sD, int mode,
                                                const float* __restrict__ u,
                                                const float* __restrict__ cvec,
                                                const float* __restrict__ r,
                                                const float* __restrict__ hb) {
    const int n0 = blockIdx.x * 128, m0 = blockIdx.y * 128, bz = blockIdx.z;
    const ushort* Ab = A + (long)bz * sA;
    const ushort* Bb = B + (long)bz * sB;
    ushort* Db = D + (long)bz * sD;
    const int tid = threadIdx.x, wave = tid >> 6, lane = tid & 63;
    const int wr = (wave >> 1) * 64, wc = (wave & 1) * 64;
    const int m = lane & 15, q8 = (lane >> 4) * 8;
    f32x4 acc[4][4];
    #pragma unroll
    for (int a = 0; a < 4; ++a)
        #pragma unroll
        for (int q = 0; q < 4; ++q) acc[a][q] = (f32x4){0.f, 0.f, 0.f, 0.f};
    #pragma unroll
    for (int kk = 0; kk < 8; ++kk) {
        short8 af[4], bfv[4];
        #pragma unroll
        for (int a = 0; a < 4; ++a)
            af[a] = *(const short8*)&Ab[(long)(m0 + wr + a * 16 + m) * 256 + kk * 32 + q8];
        #pragma unroll
        for (int q = 0; q < 4; ++q)
            bfv[q] = *(const short8*)&Bb[(long)(n0 + wc + q * 16 + m) * 256 + kk * 32 + q8];
        #pragma unroll
        for (int a = 0; a < 4; ++a)
            #pragma unroll
            for (int q = 0; q < 4; ++q)
                acc[a][q] = MFMA16(af[a], bfv[q], acc[a][q]);
    }
    const int rq = (lane >> 4) * 4;
    #pragma unroll
    for (int a = 0; a < 4; ++a) {
        #pragma unroll
        for (int q = 0; q < 4; ++q) {
            const int col = n0 + wc + q * 16 + m;
            #pragma unroll
            for (int reg = 0; reg < 4; ++reg) {
                const int row = m0 + wr + a * 16 + rq + reg;
                const float v = acc[a][q][reg];
                if (mode == 0) {
                    Db[(long)col * 256 + row] = f2bf(v);
                } else {
                    const float rv = r[col];
                    const float t2 = hb[bz * 256 + col] + 4096.0f * rv;
                    const float val = SCALEV * (v + u[bz * 256 + row] * rv + cvec[512 + row] * t2);
                    Db[(long)row * 256 + col] = f2bf(val);
                }
            }
        }
    }
}

// ---- out_b = T_b x_b + off_b via MFMA; 64-pixel tiles; grid (64, 8) ----
__global__ __launch_bounds__(256) void out_mfma(const ushort* __restrict__ Tbf,
                                                const float* __restrict__ x,
                                                const float* __restrict__ offv,
                                                float* __restrict__ out) {
    __shared__ __align__(16) ushort Bs[64 * 264];
    const int tid = threadIdx.x;
    const int p0 = blockIdx.x * 64;
    const int b = blockIdx.y;
    const float* xb = x + (long)b * CC * NPIX;
    const ushort* Tb = Tbf + (long)b * 65536;

    const int c = tid & 15, kq = tid >> 4;
    #pragma unroll
    for (int kt = 0; kt < 4; ++kt) {
        const int k4 = kt * 64 + kq * 4;
        const int p = c * 4;
        const float4 v0 = *(const float4*)&xb[(long)(k4 + 0) * NPIX + p0 + p];
        const float4 v1 = *(const float4*)&xb[(long)(k4 + 1) * NPIX + p0 + p];
        const float4 v2 = *(const float4*)&xb[(long)(k4 + 2) * NPIX + p0 + p];
        const float4 v3 = *(const float4*)&xb[(long)(k4 + 3) * NPIX + p0 + p];
        ushort4 w;
        w.x = f2bf(v0.x); w.y = f2bf(v1.x); w.z = f2bf(v2.x); w.w = f2bf(v3.x);
        *(ushort4*)&Bs[(p + 0) * 264 + k4] = w;
        w.x = f2bf(v0.y); w.y = f2bf(v1.y); w.z = f2bf(v2.y); w.w = f2bf(v3.y);
        *(ushort4*)&Bs[(p + 1) * 264 + k4] = w;
        w.x = f2bf(v0.z); w.y = f2bf(v1.z); w.z = f2bf(v2.z); w.w = f2bf(v3.z);
        *(ushort4*)&Bs[(p + 2) * 264 + k4] = w;
        w.x = f2bf(v0.w); w.y = f2bf(v1.w); w.z = f2bf(v2.w); w.w = f2bf(v3.w);
        *(ushort4*)&Bs[(p + 3) * 264 + k4] = w;
    }
    __syncthreads();

    const int wave = tid >> 6, lane = tid & 63;
    const int wr = wave * 64;
    const int m = lane & 15, q8 = (lane >> 4) * 8;
    f32x4 acc[4][4];
    #pragma unroll
    for (int a = 0; a < 4; ++a)
        #pragma unroll
        for (int q = 0; q < 4; ++q) acc[a][q] = (f32x4){0.f, 0.f, 0.f, 0.f};

    #pragma unroll
    for (int kk = 0; kk < 8; ++kk) {
        short8 af[4], bfv[4];
        #pragma unroll
        for (int a = 0; a < 4; ++a)
            af[a] = *(const short8*)&Tb[(long)(wr + a * 16 + m) * 256 + kk * 32 + q8];
        #pragma unroll
        for (int q = 0; q < 4; ++q)
            bfv[q] = *(const short8*)&Bs[(q * 16 + m) * 264 + kk * 32 + q8];
        #pragma unroll
        for (int a = 0; a < 4; ++a)
            #pragma unroll
            for (int q = 0; q < 4; ++q)
                acc[a][q] = MFMA16(af[a], bfv[q], acc[a][q]);
    }

    const int rq = (lane >> 4) * 4;
    #pragma unroll
    for (int a = 0; a < 4; ++a) {
        #pragma unroll
        for (int reg = 0; reg < 4; ++reg) {
            const int row = wr + a * 16 + rq + reg;
            const float off_ = offv[b * CC + row];
            float* orow = &out[((long)b * CC + row) * NPIX + p0];
            #pragma unroll
            for (int q = 0; q < 4; ++q)
                orow[q * 16 + m] = acc[a][q][reg] + off_;
        }
    }
}

extern "C" void kernel_launch(void* const* d_in, const int* in_sizes, int n_in,
                              void* d_out, int out_size, void* d_ws, size_t ws_size,
                              hipStream_t stream) {
    const float* x     = (const float*)d_in[0];
    const float* Wq    = (const float*)d_in[1];
    const float* bq    = (const float*)d_in[2];
    const float* gq    = (const float*)d_in[3];
    const float* betaq = (const float*)d_in[4];
    const float* Wk    = (const float*)d_in[5];
    const float* bk    = (const float*)d_in[6];
    const float* gk    = (const float*)d_in[7];
    const float* betak = (const float*)d_in[8];
    const float* Wv    = (const float*)d_in[9];
    const float* bv    = (const float*)d_in[10];
    const float* gv    = (const float*)d_in[11];
    const float* betav = (const float*)d_in[12];
    float* ws = (float*)d_ws;

    float*  G    = ws + OFF_G;
    float*  S    = ws + OFF_S;
    float*  Ghat = ws + OFF_GHAT;
    float*  xbar = ws + OFF_XBAR;
    float*  Wp   = ws + OFF_WP;
    float*  WkTf = ws + OFF_WKTF;
    float*  WvTf = ws + OFF_WVTF;
    float*  cvec = ws + OFF_CVEC;
    float*  U    = ws + OFF_U;
    float*  W2   = ws + OFF_W2;
    float*  Hb   = ws + OFF_HB;
    float*  Gy   = ws + OFF_GY;
    float*  Y    = ws + OFF_Y;
    float*  R    = ws + OFF_R;
    float*  OffV = ws + OFF_OFFV;
    ushort* Gbf  = (ushort*)(ws + OFF_GBF);
    ushort* WqT  = (ushort*)(ws + OFF_WQT);
    ushort* WkT  = (ushort*)(ws + OFF_WKT);
    ushort* Wvb  = (ushort*)(ws + OFF_WVB);
    ushort* ZT   = (ushort*)(ws + OFF_ZT);
    ushort* FT   = (ushort*)(ws + OFF_FT);
    ushort* Tbf  = (ushort*)(ws + OFF_TBF);

    // zero atomicAdd targets (G, S)
    hipMemsetAsync(d_ws, 0, (size_t)(OFF_S + BB * CC) * sizeof(float), stream);

    gram_mfma<<<dim3(8, 8, 10), 256, 0, stream>>>(x, G, S);
    mirror_t<<<17, 256, 0, stream>>>(G, S, Ghat, xbar, Gbf);
    stats_quad<<<dim3(256, 3), 256, 0, stream>>>(Wq, Wk, Wv, Ghat, xbar,
                                                 bq, gq, betaq, bk, gk, betak,
                                                 bv, gv, betav, Wp, cvec,
                                                 WqT, WkT, Wvb, WkTf, WvTf);
    // Z = Wk'^T Wq'  -> ZT
    gemm_mid<<<dim3(2, 2, 1), 256, 0, stream>>>(WkT, 0L, WqT, 0L, ZT, 0L, 0,
                                                nullptr, nullptr, nullptr, nullptr);
    mid_a<<<9, 256, 0, stream>>>(Wp, WkTf, WvTf, S, cvec, U, W2, Y, R);
    mid_b<<<8, 256, 0, stream>>>(Wp, G, W2, Y, Hb, Gy);
    // F_b = G_b Z -> FT
    gemm_mid<<<dim3(2, 2, 8), 256, 0, stream>>>(Gbf, 65536L, ZT, 0L, FT, 65536L, 0,
                                                nullptr, nullptr, nullptr, nullptr);
    mid_c<<<8, 256, 0, stream>>>(WvTf, Gy, U, W2, cvec, OffV);
    // T_b = Wv' F_b + rank-1, scaled -> Tbf
    gemm_mid<<<dim3(2, 2, 8), 256, 0, stream>>>(Wvb, 0L, FT, 65536L, Tbf, 65536L, 1,
                                                U, cvec, R, Hb);
    out_mfma<<<dim3(64, 8), 256, 0, stream>>>(Tbf, x, OffV, (float*)d_out);
}

// Round 6
// 258.964 us; speedup vs baseline: 1.0098x; 1.0098x over previous
//
#include <hip/hip_runtime.h>
#include <hip/hip_bf16.h>

// PatchAttentionLayer, restructured:
//   G_b = x_b x_b^T (Gram, bf16 MFMA, 128x128 upper tiles + mirror), s_b = x_b 1
//   BN stats analytic (quadratic form on Ghat); Wp = diag(a)W, cvec.
//   Z = Wk'^T Wq'; F_b = G_b Z; T_b = Wv' F_b + rank-1; out = T_b x_b + off 1^T.
// R6: gram 128-tiles (halves x re-reads), packed v_cvt_pk_bf16_f32 staging,
// mid_b+mid_c merged.

#define BB 8
#define CC 256
#define NPIX 4096
#define PTOT 32768
#define EPSV 1e-5f
#define SCALEV 0.125f

// ---- workspace layout (float offsets; ushort buffers = count/2 floats) ----
#define OFF_G     0L          // 524288
#define OFF_S     524288L     // 2048
#define OFF_GHAT  526336L     // 65536
#define OFF_XBAR  591872L     // 256
#define OFF_WP    592128L     // 196608
#define OFF_WKTF  788736L     // 65536
#define OFF_WVTF  854272L     // 65536
#define OFF_CVEC  919808L     // 768
#define OFF_U     920576L     // 2048
#define OFF_W2    922624L     // 2048
#define OFF_HB    924672L     // 2048
#define OFF_Y     926720L     // 256
#define OFF_R     926976L     // 256
#define OFF_OFFV  927232L     // 2048
#define OFF_GBF   929280L     // 8*65536 ushort = 262144 floats
#define OFF_WQT   1191424L    // 32768
#define OFF_WKT   1224192L    // 32768
#define OFF_WVB   1256960L    // 32768
#define OFF_ZT    1289728L    // 32768
#define OFF_FT    1322496L    // 262144
#define OFF_TBF   1584640L    // 262144
// total 1846784 floats = 7.39 MB

typedef __attribute__((ext_vector_type(8))) short short8;
typedef __attribute__((ext_vector_type(4))) float f32x4;

#define MFMA16(a, b, c) __builtin_amdgcn_mfma_f32_16x16x32_bf16((a), (b), (c), 0, 0, 0)

__device__ __forceinline__ ushort f2bf(float f) {
    union { float f; unsigned u; } v; v.f = f;
    const unsigned r = (v.u + 0x7FFFu + ((v.u >> 16) & 1u)) >> 16;
    return (ushort)r;
}

// packed RNE f32x2 -> bf16x2 (v_cvt_pk_bf16_f32 on gfx950)
__device__ __forceinline__ ushort2 f2bf2(float a, float b) {
    __hip_bfloat162 h = __float22bfloat162_rn(float2{a, b});
    union { __hip_bfloat162 h; ushort2 u; } v; v.h = h;
    return v.u;
}

__device__ __forceinline__ float block_reduce(float v, float* red, int tid) {
    red[tid] = v; __syncthreads();
    for (int st = 128; st > 0; st >>= 1) {
        if (tid < st) red[tid] += red[tid + st];
        __syncthreads();
    }
    float r = red[0]; __syncthreads();
    return r;
}

// ---- Gram via MFMA: 128x128 upper-triangle tiles, ks=8 K-split, rowsum fused ----
// grid (8 ks, 8 b, 3 tt): tt=0 -> (0,0); tt=1 -> (1,1); tt=2 -> (0,1)
__global__ __launch_bounds__(256) void gram_mfma(const float* __restrict__ x,
                                                 float* __restrict__ G,
                                                 float* __restrict__ S) {
    __shared__ __align__(16) ushort Ab[128 * 72];
    __shared__ __align__(16) ushort Bb[128 * 72];
    __shared__ float rs[128];
    const int tid = threadIdx.x;
    const int ks = blockIdx.x, b = blockIdx.y, tt = blockIdx.z;
    const int it = (tt == 1) ? 1 : 0;
    const int jt = (tt == 0) ? 0 : 1;
    const bool diag = (tt < 2);
    const int i0 = it * 128, j0 = jt * 128, k0 = ks * 512;
    const float* xb = x + (long)b * CC * NPIX;
    const int c = tid & 15, rp = tid >> 4;       // 16 col-groups x 16 row-groups
    const int wave = tid >> 6, lane = tid & 63;
    const int wr = (wave >> 1) * 64, wc = (wave & 1) * 64;
    const int m = lane & 15, q8 = (lane >> 4) * 8;

    if (tid < 128) rs[tid] = 0.f;
    float rloc[8] = {};
    f32x4 acc[4][4];
    #pragma unroll
    for (int a = 0; a < 4; ++a)
        #pragma unroll
        for (int q = 0; q < 4; ++q) acc[a][q] = (f32x4){0.f, 0.f, 0.f, 0.f};

    for (int kc = 0; kc < 512; kc += 64) {
        __syncthreads();
        #pragma unroll
        for (int pp = 0; pp < 8; ++pp) {
            const int row = pp * 16 + rp;
            const float4 v = *(const float4*)&xb[(long)(i0 + row) * NPIX + k0 + kc + c * 4];
            rloc[pp] += v.x + v.y + v.z + v.w;
            const ushort2 w01 = f2bf2(v.x, v.y);
            const ushort2 w23 = f2bf2(v.z, v.w);
            ushort4 w; w.x = w01.x; w.y = w01.y; w.z = w23.x; w.w = w23.y;
            *(ushort4*)&Ab[row * 72 + c * 4] = w;
        }
        if (!diag) {
            #pragma unroll
            for (int pp = 0; pp < 8; ++pp) {
                const int row = pp * 16 + rp;
                const float4 v = *(const float4*)&xb[(long)(j0 + row) * NPIX + k0 + kc + c * 4];
                const ushort2 w01 = f2bf2(v.x, v.y);
                const ushort2 w23 = f2bf2(v.z, v.w);
                ushort4 w; w.x = w01.x; w.y = w01.y; w.z = w23.x; w.w = w23.y;
                *(ushort4*)&Bb[row * 72 + c * 4] = w;
            }
        }
        __syncthreads();
        const ushort* Bsrc = diag ? Ab : Bb;
        #pragma unroll
        for (int kk = 0; kk < 2; ++kk) {
            short8 af[4], bfv[4];
            #pragma unroll
            for (int a = 0; a < 4; ++a)
                af[a] = *(const short8*)&Ab[(wr + a * 16 + m) * 72 + kk * 32 + q8];
            #pragma unroll
            for (int q = 0; q < 4; ++q)
                bfv[q] = *(const short8*)&Bsrc[(wc + q * 16 + m) * 72 + kk * 32 + q8];
            #pragma unroll
            for (int a = 0; a < 4; ++a)
                #pragma unroll
                for (int q = 0; q < 4; ++q)
                    acc[a][q] = MFMA16(af[a], bfv[q], acc[a][q]);
        }
    }
    if (diag) {
        #pragma unroll
        for (int pp = 0; pp < 8; ++pp) atomicAdd(&rs[pp * 16 + rp], rloc[pp]);
        __syncthreads();
        if (tid < 128) atomicAdd(&S[b * CC + i0 + tid], rs[tid]);
    }
    float* Gb = G + (long)b * 65536;
    const int rq = (lane >> 4) * 4;
    #pragma unroll
    for (int a = 0; a < 4; ++a) {
        #pragma unroll
        for (int q = 0; q < 4; ++q) {
            const int gj = j0 + wc + q * 16 + m;
            #pragma unroll
            for (int reg = 0; reg < 4; ++reg)
                atomicAdd(&Gb[(long)(i0 + wr + a * 16 + rq + reg) * 256 + gj], acc[a][q][reg]);
        }
    }
}

// ---- mirror via LDS-tile transpose; Gbf; Ghat; xbar. grid 17 blocks ----
__global__ __launch_bounds__(256) void mirror_t(float* __restrict__ G,
                                                const float* __restrict__ S,
                                                float* __restrict__ Ghat,
                                                float* __restrict__ xbar,
                                                ushort* __restrict__ Gbf) {
    const int blk = blockIdx.x, tid = threadIdx.x;
    if (blk == 16) {
        float sum = 0.f;
        for (int b = 0; b < BB; ++b) sum += S[b * CC + tid];
        xbar[tid] = sum * (1.0f / PTOT);
        return;
    }
    const int ti = blk >> 2, tj = blk & 3;
    const int r = tid >> 2, c4 = (tid & 3) * 16;
    float gacc[16] = {};
    if (ti <= tj) {
        const long rowbase = (long)(ti * 64 + r) * 256 + tj * 64 + c4;
        for (int b = 0; b < BB; ++b) {
            const float* Gb = G + (long)b * 65536;
            ushort* Qb = Gbf + (long)b * 65536;
            #pragma unroll
            for (int k = 0; k < 4; ++k) {
                const float4 v = *(const float4*)&Gb[rowbase + k * 4];
                ushort4 w;
                w.x = f2bf(v.x); w.y = f2bf(v.y); w.z = f2bf(v.z); w.w = f2bf(v.w);
                *(ushort4*)&Qb[rowbase + k * 4] = w;
                gacc[k * 4 + 0] += v.x; gacc[k * 4 + 1] += v.y;
                gacc[k * 4 + 2] += v.z; gacc[k * 4 + 3] += v.w;
            }
        }
        #pragma unroll
        for (int k = 0; k < 16; ++k) Ghat[rowbase + k] = gacc[k] * (1.0f / PTOT);
    } else {
        __shared__ float tile[64 * 68];
        const long srcbase = (long)(tj * 64 + r) * 256 + ti * 64 + c4;
        const long dstbase = (long)(ti * 64 + r) * 256 + tj * 64 + c4;
        for (int b = 0; b < BB; ++b) {
            float* Gb = G + (long)b * 65536;
            ushort* Qb = Gbf + (long)b * 65536;
            #pragma unroll
            for (int k = 0; k < 4; ++k)
                *(float4*)&tile[r * 68 + c4 + k * 4] = *(const float4*)&Gb[srcbase + k * 4];
            __syncthreads();
            #pragma unroll
            for (int k = 0; k < 4; ++k) {
                float4 v;
                v.x = tile[(c4 + k * 4 + 0) * 68 + r];
                v.y = tile[(c4 + k * 4 + 1) * 68 + r];
                v.z = tile[(c4 + k * 4 + 2) * 68 + r];
                v.w = tile[(c4 + k * 4 + 3) * 68 + r];
                *(float4*)&Gb[dstbase + k * 4] = v;
                ushort4 w;
                w.x = f2bf(v.x); w.y = f2bf(v.y); w.z = f2bf(v.z); w.w = f2bf(v.w);
                *(ushort4*)&Qb[dstbase + k * 4] = w;
                gacc[k * 4 + 0] += v.x; gacc[k * 4 + 1] += v.y;
                gacc[k * 4 + 2] += v.z; gacc[k * 4 + 3] += v.w;
            }
            __syncthreads();
        }
        #pragma unroll
        for (int k = 0; k < 16; ++k) Ghat[dstbase + k] = gacc[k] * (1.0f / PTOT);
    }
}

// ---- BN stats; writes fp32 Wp (+ fp32 transposes of Wk',Wv'), bf16 mats, cvec ----
__global__ void stats_quad(const float* __restrict__ Wq, const float* __restrict__ Wk,
                           const float* __restrict__ Wv, const float* __restrict__ Ghat,
                           const float* __restrict__ xbar,
                           const float* bq, const float* gq, const float* betaq,
                           const float* bk, const float* gk, const float* betak,
                           const float* bv, const float* gv, const float* betav,
                           float* __restrict__ Wp, float* __restrict__ cvec,
                           ushort* __restrict__ WqT, ushort* __restrict__ WkT,
                           ushort* __restrict__ Wvb, float* __restrict__ WkTf,
                           float* __restrict__ WvTf) {
    const int o = blockIdx.x, t = blockIdx.y, tid = threadIdx.x;
    const float* Wt  = t == 0 ? Wq : (t == 1 ? Wk : Wv);
    const float* bt  = t == 0 ? bq : (t == 1 ? bk : bv);
    const float* gt  = t == 0 ? gq : (t == 1 ? gk : gv);
    const float* bet = t == 0 ? betaq : (t == 1 ? betak : betav);
    __shared__ float wrow[256];
    __shared__ float red[256];
    wrow[tid] = Wt[o * 256 + tid];
    __syncthreads();
    const float* grow = Ghat + (long)tid * 256;
    float tj = 0.f;
    #pragma unroll 8
    for (int k = 0; k < 256; k += 4) {
        const float4 g = *(const float4*)&grow[k];
        tj += g.x * wrow[k] + g.y * wrow[k + 1] + g.z * wrow[k + 2] + g.w * wrow[k + 3];
    }
    const float q2 = block_reduce(wrow[tid] * tj, red, tid);
    const float wx = block_reduce(wrow[tid] * xbar[tid], red, tid);
    const float bo = bt[o];
    const float mu = wx + bo;
    const float var = q2 + 2.f * bo * mu - bo * bo - mu * mu;
    const float a = gt[o] * rsqrtf(var + EPSV);
    const float wpv = a * wrow[tid];
    Wp[(long)t * 65536 + o * 256 + tid] = wpv;
    const ushort wb = f2bf(wpv);
    if (t == 0) {
        WqT[(long)tid * 256 + o] = wb;
    } else if (t == 1) {
        WkT[(long)tid * 256 + o] = wb;
        WkTf[(long)tid * 256 + o] = wpv;
    } else {
        Wvb[(long)o * 256 + tid] = wb;
        WvTf[(long)tid * 256 + o] = wpv;
    }
    if (tid == 0) cvec[t * 256 + o] = a * (bo - mu) + bet[o];
}

// ---- mid_a: u_b = Wv' s_b, w_b = Wk' s_b (blocks 0-7); y, r (block 8) ----
__global__ __launch_bounds__(256) void mid_a(const float* __restrict__ Wp,
                                             const float* __restrict__ WkTf,
                                             const float* __restrict__ WvTf,
                                             const float* __restrict__ S,
                                             const float* __restrict__ cvec,
                                             float* __restrict__ u, float* __restrict__ w,
                                             float* __restrict__ y, float* __restrict__ r) {
    const int bidx = blockIdx.x, tid = threadIdx.x;
    if (bidx < 8) {
        __shared__ float sh[256];
        sh[tid] = S[bidx * 256 + tid]; __syncthreads();
        float uu = 0.f, ww = 0.f;
        #pragma unroll 8
        for (int j = 0; j < 256; ++j) {
            uu += WvTf[(long)j * 256 + tid] * sh[j];
            ww += WkTf[(long)j * 256 + tid] * sh[j];
        }
        u[bidx * 256 + tid] = uu;
        w[bidx * 256 + tid] = ww;
    } else {
        __shared__ float cqs[256], cks[256];
        cqs[tid] = cvec[tid]; cks[tid] = cvec[256 + tid]; __syncthreads();
        float yy = 0.f, rr = 0.f;
        #pragma unroll 8
        for (int o = 0; o < 256; ++o) {
            yy += Wp[65536L + (long)o * 256 + tid] * cqs[o];
            rr += Wp[(long)o * 256 + tid] * cks[o];
        }
        y[tid] = yy;
        r[tid] = rr;
    }
}

// ---- mid_bc: h_b = Wq'^T w_b ; gy_b = G_b y ; vg_b = Wv' gy_b ; offv ----
__global__ __launch_bounds__(256) void mid_bc(const float* __restrict__ Wp,
                                              const float* __restrict__ G,
                                              const float* __restrict__ WvTf,
                                              const float* __restrict__ w,
                                              const float* __restrict__ y,
                                              const float* __restrict__ u,
                                              const float* __restrict__ cvec,
                                              float* __restrict__ hb,
                                              float* __restrict__ offv) {
    const int b = blockIdx.x, tid = threadIdx.x;
    __shared__ float wl[256], yl[256], gyl[256], red[256], cqs[256], cks[256];
    wl[tid] = w[b * 256 + tid];
    yl[tid] = y[tid];
    cqs[tid] = cvec[tid];
    cks[tid] = cvec[256 + tid];
    const float cv = cvec[512 + tid];
    const float uu = u[b * 256 + tid];
    __syncthreads();
    float hh = 0.f, gg = 0.f;
    #pragma unroll 8
    for (int o = 0; o < 256; ++o) {
        hh += Wp[(long)o * 256 + tid] * wl[o];
        gg += G[(long)b * 65536 + (long)o * 256 + tid] * yl[o];
    }
    hb[b * 256 + tid] = hh;
    gyl[tid] = gg;
    __syncthreads();
    float vg = 0.f;
    #pragma unroll 8
    for (int j = 0; j < 256; ++j) vg += WvTf[(long)j * 256 + tid] * gyl[j];
    const float dkq = block_reduce(cqs[tid] * cks[tid], red, tid);
    const float dwq = block_reduce(wl[tid] * cqs[tid], red, tid);
    offv[b * 256 + tid] = SCALEV * (vg + uu * dkq + cv * (dwq + 4096.0f * dkq));
}

// ---- bf16 MFMA 128x128-tile GEMM, K=256, fragments direct from L2 ----
// mode 0: store D^T plain bf16.  mode 1: rank-1 epilogue + scale, row-major.
__global__ __launch_bounds__(256) void gemm_mid(const ushort* __restrict__ A, long sA,
                                                const ushort* __restrict__ B, long sB,
                                                ushort* __restrict__ D, long sD, int mode,
                                                const float* __restrict__ u,
                                                const float* __restrict__ cvec,
                                                const float* __restrict__ r,
                                                const float* __restrict__ hb) {
    const int n0 = blockIdx.x * 128, m0 = blockIdx.y * 128, bz = blockIdx.z;
    const ushort* Ab = A + (long)bz * sA;
    const ushort* Bb = B + (long)bz * sB;
    ushort* Db = D + (long)bz * sD;
    const int tid = threadIdx.x, wave = tid >> 6, lane = tid & 63;
    const int wr = (wave >> 1) * 64, wc = (wave & 1) * 64;
    const int m = lane & 15, q8 = (lane >> 4) * 8;
    f32x4 acc[4][4];
    #pragma unroll
    for (int a = 0; a < 4; ++a)
        #pragma unroll
        for (int q = 0; q < 4; ++q) acc[a][q] = (f32x4){0.f, 0.f, 0.f, 0.f};
    #pragma unroll
    for (int kk = 0; kk < 8; ++kk) {
        short8 af[4], bfv[4];
        #pragma unroll
        for (int a = 0; a < 4; ++a)
            af[a] = *(const short8*)&Ab[(long)(m0 + wr + a * 16 + m) * 256 + kk * 32 + q8];
        #pragma unroll
        for (int q = 0; q < 4; ++q)
            bfv[q] = *(const short8*)&Bb[(long)(n0 + wc + q * 16 + m) * 256 + kk * 32 + q8];
        #pragma unroll
        for (int a = 0; a < 4; ++a)
            #pragma unroll
            for (int q = 0; q < 4; ++q)
                acc[a][q] = MFMA16(af[a], bfv[q], acc[a][q]);
    }
    const int rq = (lane >> 4) * 4;
    #pragma unroll
    for (int a = 0; a < 4; ++a) {
        #pragma unroll
        for (int q = 0; q < 4; ++q) {
            const int col = n0 + wc + q * 16 + m;
            #pragma unroll
            for (int reg = 0; reg < 4; ++reg) {
                const int row = m0 + wr + a * 16 + rq + reg;
                const float v = acc[a][q][reg];
                if (mode == 0) {
                    Db[(long)col * 256 + row] = f2bf(v);
                } else {
                    const float rv = r[col];
                    const float t2 = hb[bz * 256 + col] + 4096.0f * rv;
                    const float val = SCALEV * (v + u[bz * 256 + row] * rv + cvec[512 + row] * t2);
                    Db[(long)row * 256 + col] = f2bf(val);
                }
            }
        }
    }
}

// ---- out_b = T_b x_b + off_b via MFMA; 64-pixel tiles; grid (64, 8) ----
__global__ __launch_bounds__(256) void out_mfma(const ushort* __restrict__ Tbf,
                                                const float* __restrict__ x,
                                                const float* __restrict__ offv,
                                                float* __restrict__ out) {
    __shared__ __align__(16) ushort Bs[64 * 264];
    const int tid = threadIdx.x;
    const int p0 = blockIdx.x * 64;
    const int b = blockIdx.y;
    const float* xb = x + (long)b * CC * NPIX;
    const ushort* Tb = Tbf + (long)b * 65536;

    const int c = tid & 15, kq = tid >> 4;
    #pragma unroll
    for (int kt = 0; kt < 4; ++kt) {
        const int k4 = kt * 64 + kq * 4;
        const int p = c * 4;
        const float4 v0 = *(const float4*)&xb[(long)(k4 + 0) * NPIX + p0 + p];
        const float4 v1 = *(const float4*)&xb[(long)(k4 + 1) * NPIX + p0 + p];
        const float4 v2 = *(const float4*)&xb[(long)(k4 + 2) * NPIX + p0 + p];
        const float4 v3 = *(const float4*)&xb[(long)(k4 + 3) * NPIX + p0 + p];
        ushort2 a01, a23;
        ushort4 w;
        a01 = f2bf2(v0.x, v1.x); a23 = f2bf2(v2.x, v3.x);
        w.x = a01.x; w.y = a01.y; w.z = a23.x; w.w = a23.y;
        *(ushort4*)&Bs[(p + 0) * 264 + k4] = w;
        a01 = f2bf2(v0.y, v1.y); a23 = f2bf2(v2.y, v3.y);
        w.x = a01.x; w.y = a01.y; w.z = a23.x; w.w = a23.y;
        *(ushort4*)&Bs[(p + 1) * 264 + k4] = w;
        a01 = f2bf2(v0.z, v1.z); a23 = f2bf2(v2.z, v3.z);
        w.x = a01.x; w.y = a01.y; w.z = a23.x; w.w = a23.y;
        *(ushort4*)&Bs[(p + 2) * 264 + k4] = w;
        a01 = f2bf2(v0.w, v1.w); a23 = f2bf2(v2.w, v3.w);
        w.x = a01.x; w.y = a01.y; w.z = a23.x; w.w = a23.y;
        *(ushort4*)&Bs[(p + 3) * 264 + k4] = w;
    }
    __syncthreads();

    const int wave = tid >> 6, lane = tid & 63;
    const int wr = wave * 64;
    const int m = lane & 15, q8 = (lane >> 4) * 8;
    f32x4 acc[4][4];
    #pragma unroll
    for (int a = 0; a < 4; ++a)
        #pragma unroll
        for (int q = 0; q < 4; ++q) acc[a][q] = (f32x4){0.f, 0.f, 0.f, 0.f};

    #pragma unroll
    for (int kk = 0; kk < 8; ++kk) {
        short8 af[4], bfv[4];
        #pragma unroll
        for (int a = 0; a < 4; ++a)
            af[a] = *(const short8*)&Tb[(long)(wr + a * 16 + m) * 256 + kk * 32 + q8];
        #pragma unroll
        for (int q = 0; q < 4; ++q)
            bfv[q] = *(const short8*)&Bs[(q * 16 + m) * 264 + kk * 32 + q8];
        #pragma unroll
        for (int a = 0; a < 4; ++a)
            #pragma unroll
            for (int q = 0; q < 4; ++q)
                acc[a][q] = MFMA16(af[a], bfv[q], acc[a][q]);
    }

    const int rq = (lane >> 4) * 4;
    #pragma unroll
    for (int a = 0; a < 4; ++a) {
        #pragma unroll
        for (int reg = 0; reg < 4; ++reg) {
            const int row = wr + a * 16 + rq + reg;
            const float off_ = offv[b * CC + row];
            float* orow = &out[((long)b * CC + row) * NPIX + p0];
            #pragma unroll
            for (int q = 0; q < 4; ++q)
                orow[q * 16 + m] = acc[a][q][reg] + off_;
        }
    }
}

extern "C" void kernel_launch(void* const* d_in, const int* in_sizes, int n_in,
                              void* d_out, int out_size, void* d_ws, size_t ws_size,
                              hipStream_t stream) {
    const float* x     = (const float*)d_in[0];
    const float* Wq    = (const float*)d_in[1];
    const float* bq    = (const float*)d_in[2];
    const float* gq    = (const float*)d_in[3];
    const float* betaq = (const float*)d_in[4];
    const float* Wk    = (const float*)d_in[5];
    const float* bk    = (const float*)d_in[6];
    const float* gk    = (const float*)d_in[7];
    const float* betak = (const float*)d_in[8];
    const float* Wv    = (const float*)d_in[9];
    const float* bv    = (const float*)d_in[10];
    const float* gv    = (const float*)d_in[11];
    const float* betav = (const float*)d_in[12];
    float* ws = (float*)d_ws;

    float*  G    = ws + OFF_G;
    float*  S    = ws + OFF_S;
    float*  Ghat = ws + OFF_GHAT;
    float*  xbar = ws + OFF_XBAR;
    float*  Wp   = ws + OFF_WP;
    float*  WkTf = ws + OFF_WKTF;
    float*  WvTf = ws + OFF_WVTF;
    float*  cvec = ws + OFF_CVEC;
    float*  U    = ws + OFF_U;
    float*  W2   = ws + OFF_W2;
    float*  Hb   = ws + OFF_HB;
    float*  Y    = ws + OFF_Y;
    float*  R    = ws + OFF_R;
    float*  OffV = ws + OFF_OFFV;
    ushort* Gbf  = (ushort*)(ws + OFF_GBF);
    ushort* WqT  = (ushort*)(ws + OFF_WQT);
    ushort* WkT  = (ushort*)(ws + OFF_WKT);
    ushort* Wvb  = (ushort*)(ws + OFF_WVB);
    ushort* ZT   = (ushort*)(ws + OFF_ZT);
    ushort* FT   = (ushort*)(ws + OFF_FT);
    ushort* Tbf  = (ushort*)(ws + OFF_TBF);

    // zero atomicAdd targets (G, S)
    hipMemsetAsync(d_ws, 0, (size_t)(OFF_S + BB * CC) * sizeof(float), stream);

    gram_mfma<<<dim3(8, 8, 3), 256, 0, stream>>>(x, G, S);
    mirror_t<<<17, 256, 0, stream>>>(G, S, Ghat, xbar, Gbf);
    stats_quad<<<dim3(256, 3), 256, 0, stream>>>(Wq, Wk, Wv, Ghat, xbar,
                                                 bq, gq, betaq, bk, gk, betak,
                                                 bv, gv, betav, Wp, cvec,
                                                 WqT, WkT, Wvb, WkTf, WvTf);
    // Z = Wk'^T Wq'  -> ZT
    gemm_mid<<<dim3(2, 2, 1), 256, 0, stream>>>(WkT, 0L, WqT, 0L, ZT, 0L, 0,
                                                nullptr, nullptr, nullptr, nullptr);
    mid_a<<<9, 256, 0, stream>>>(Wp, WkTf, WvTf, S, cvec, U, W2, Y, R);
    mid_bc<<<8, 256, 0, stream>>>(Wp, G, WvTf, W2, Y, U, cvec, Hb, OffV);
    // F_b = G_b Z -> FT
    gemm_mid<<<dim3(2, 2, 8), 256, 0, stream>>>(Gbf, 65536L, ZT, 0L, FT, 65536L, 0,
                                                nullptr, nullptr, nullptr, nullptr);
    // T_b = Wv' F_b + rank-1, scaled -> Tbf
    gemm_mid<<<dim3(2, 2, 8), 256, 0, stream>>>(Wvb, 0L, FT, 65536L, Tbf, 65536L, 1,
                                                U, cvec, R, Hb);
    out_mfma<<<dim3(64, 8), 256, 0, stream>>>(Tbf, x, OffV, (float*)d_out);
}

// Round 7
// 213.512 us; speedup vs baseline: 1.2248x; 1.2129x over previous
//
#include <hip/hip_runtime.h>
#include <hip/hip_bf16.h>

// PatchAttentionLayer, restructured (R7):
//   gram: per-block fp32 partial tiles (NO atomics, no memset), partial rowsums.
//   reduce_mirror: sum partials -> Gbf (bf16, full via LDS-transpose mirror),
//                  Ghat (fp32), S, xbar. fp32 G never materialized.
//   stats: BN stats analytic (quadratic form on Ghat) -> Wp, W transposes, cvec.
//   zmida: {Z = Wk'^T Wq' (MFMA) | mid_a matvecs} fused.
//   bcF:   {mid_bc (offv, hb; reads Gbf) | F_b = G_b Z (MFMA)} fused.
//   gemm_T: T_b = Wv' F_b + rank-1 epilogue -> bf16 T.
//   out: out_b = T_b x_b + off 1^T (MFMA).
// 7 dispatches total.

#define BB 8
#define CC 256
#define NPIX 4096
#define PTOT 32768
#define EPSV 1e-5f
#define SCALEV 0.125f

// ---- workspace layout (float offsets) ----
#define OFF_PG    0L          // 192*16384 = 3145728 (gram partials)
#define OFF_SP    3145728L    // 16384 (rowsum partials)
#define OFF_S     3162112L    // 2048
#define OFF_GHAT  3164160L    // 65536
#define OFF_XBAR  3229696L    // 256
#define OFF_WP    3229952L    // 196608
#define OFF_WKTF  3426560L    // 65536
#define OFF_WVTF  3492096L    // 65536
#define OFF_CVEC  3557632L    // 768
#define OFF_U     3558400L    // 2048
#define OFF_W2    3560448L    // 2048
#define OFF_HB    3562496L    // 2048
#define OFF_Y     3564544L    // 256
#define OFF_R     3564800L    // 256
#define OFF_OFFV  3565056L    // 2048
#define OFF_GBF   3567104L    // 8*65536 ushort = 262144 floats
#define OFF_WQT   3829248L    // 32768
#define OFF_WKT   3862016L    // 32768
#define OFF_WVB   3894784L    // 32768
#define OFF_ZT    3927552L    // 32768
#define OFF_FT    3960320L    // 262144
#define OFF_TBF   4222464L    // 262144
// total 4484608 floats = 17.9 MB

typedef __attribute__((ext_vector_type(8))) short short8;
typedef __attribute__((ext_vector_type(4))) float f32x4;

#define MFMA16(a, b, c) __builtin_amdgcn_mfma_f32_16x16x32_bf16((a), (b), (c), 0, 0, 0)

__device__ __forceinline__ ushort f2bf(float f) {
    union { float f; unsigned u; } v; v.f = f;
    const unsigned r = (v.u + 0x7FFFu + ((v.u >> 16) & 1u)) >> 16;
    return (ushort)r;
}

__device__ __forceinline__ float bf2f(ushort u) {
    union { unsigned u; float f; } v; v.u = ((unsigned)u) << 16;
    return v.f;
}

// packed RNE f32x2 -> bf16x2 (v_cvt_pk_bf16_f32 on gfx950)
__device__ __forceinline__ ushort2 f2bf2(float a, float b) {
    __hip_bfloat162 h = __float22bfloat162_rn(float2{a, b});
    union { __hip_bfloat162 h; ushort2 u; } v; v.h = h;
    return v.u;
}

__device__ __forceinline__ float block_reduce(float v, float* red, int tid) {
    red[tid] = v; __syncthreads();
    for (int st = 128; st > 0; st >>= 1) {
        if (tid < st) red[tid] += red[tid + st];
        __syncthreads();
    }
    float r = red[0]; __syncthreads();
    return r;
}

// ---- Gram via MFMA: 128x128 upper tiles, ks=8, partial-tile stores, no atomics ----
// grid (8 ks, 8 b, 3 tt): tt=0 -> (0,0); tt=1 -> (1,1); tt=2 -> (0,1)
__global__ __launch_bounds__(256) void gram_mfma(const float* __restrict__ x,
                                                 float* __restrict__ Pg,
                                                 float* __restrict__ Sp) {
    __shared__ __align__(16) ushort Ab[128 * 72];
    __shared__ __align__(16) ushort Bb[128 * 72];
    __shared__ float rs[128];
    const int tid = threadIdx.x;
    const int ks = blockIdx.x, b = blockIdx.y, tt = blockIdx.z;
    const int it = (tt == 1) ? 1 : 0;
    const int jt = (tt == 0) ? 0 : 1;
    const bool diag = (tt < 2);
    const int i0 = it * 128, j0 = jt * 128, k0 = ks * 512;
    const float* xb = x + (long)b * CC * NPIX;
    const int c = tid & 15, rp = tid >> 4;
    const int wave = tid >> 6, lane = tid & 63;
    const int wr = (wave >> 1) * 64, wc = (wave & 1) * 64;
    const int m = lane & 15, q8 = (lane >> 4) * 8;

    if (tid < 128) rs[tid] = 0.f;
    float rloc[8] = {};
    f32x4 acc[4][4];
    #pragma unroll
    for (int a = 0; a < 4; ++a)
        #pragma unroll
        for (int q = 0; q < 4; ++q) acc[a][q] = (f32x4){0.f, 0.f, 0.f, 0.f};

    for (int kc = 0; kc < 512; kc += 64) {
        __syncthreads();
        #pragma unroll
        for (int pp = 0; pp < 8; ++pp) {
            const int row = pp * 16 + rp;
            const float4 v = *(const float4*)&xb[(long)(i0 + row) * NPIX + k0 + kc + c * 4];
            rloc[pp] += v.x + v.y + v.z + v.w;
            const ushort2 w01 = f2bf2(v.x, v.y);
            const ushort2 w23 = f2bf2(v.z, v.w);
            ushort4 w; w.x = w01.x; w.y = w01.y; w.z = w23.x; w.w = w23.y;
            *(ushort4*)&Ab[row * 72 + c * 4] = w;
        }
        if (!diag) {
            #pragma unroll
            for (int pp = 0; pp < 8; ++pp) {
                const int row = pp * 16 + rp;
                const float4 v = *(const float4*)&xb[(long)(j0 + row) * NPIX + k0 + kc + c * 4];
                const ushort2 w01 = f2bf2(v.x, v.y);
                const ushort2 w23 = f2bf2(v.z, v.w);
                ushort4 w; w.x = w01.x; w.y = w01.y; w.z = w23.x; w.w = w23.y;
                *(ushort4*)&Bb[row * 72 + c * 4] = w;
            }
        }
        __syncthreads();
        const ushort* Bsrc = diag ? Ab : Bb;
        #pragma unroll
        for (int kk = 0; kk < 2; ++kk) {
            short8 af[4], bfv[4];
            #pragma unroll
            for (int a = 0; a < 4; ++a)
                af[a] = *(const short8*)&Ab[(wr + a * 16 + m) * 72 + kk * 32 + q8];
            #pragma unroll
            for (int q = 0; q < 4; ++q)
                bfv[q] = *(const short8*)&Bsrc[(wc + q * 16 + m) * 72 + kk * 32 + q8];
            #pragma unroll
            for (int a = 0; a < 4; ++a)
                #pragma unroll
                for (int q = 0; q < 4; ++q)
                    acc[a][q] = MFMA16(af[a], bfv[q], acc[a][q]);
        }
    }
    if (diag) {
        #pragma unroll
        for (int pp = 0; pp < 8; ++pp) atomicAdd(&rs[pp * 16 + rp], rloc[pp]);
        __syncthreads();
        if (tid < 128) Sp[(((long)ks * 8 + b) * 2 + it) * 128 + tid] = rs[tid];
    }
    float* Pt = Pg + (((long)ks * 8 + b) * 3 + tt) * 16384;
    const int rq = (lane >> 4) * 4;
    #pragma unroll
    for (int a = 0; a < 4; ++a) {
        #pragma unroll
        for (int q = 0; q < 4; ++q) {
            const int col = wc + q * 16 + m;
            #pragma unroll
            for (int reg = 0; reg < 4; ++reg)
                Pt[(long)(wr + a * 16 + rq + reg) * 128 + col] = acc[a][q][reg];
        }
    }
}

// ---- reduce partials -> Gbf (full, mirrored), Ghat; S; xbar. grid 49 ----
__global__ __launch_bounds__(256) void reduce_mirror(const float* __restrict__ Pg,
                                                     const float* __restrict__ Sp,
                                                     ushort* __restrict__ Gbf,
                                                     float* __restrict__ Ghat,
                                                     float* __restrict__ S,
                                                     float* __restrict__ xbar) {
    const int blk = blockIdx.x, tid = threadIdx.x;
    if (blk == 48) {
        const int it2 = tid >> 7, rr = tid & 127;
        float xacc = 0.f;
        for (int b = 0; b < BB; ++b) {
            float acc = 0.f;
            #pragma unroll
            for (int ks = 0; ks < 8; ++ks)
                acc += Sp[(((long)ks * 8 + b) * 2 + it2) * 128 + rr];
            S[b * 256 + tid] = acc;
            xacc += acc;
        }
        xbar[tid] = xacc * (1.0f / PTOT);
        return;
    }
    __shared__ float tile[32][33];
    const int tt = blk >> 4, sub = blk & 15;
    const int sr = (sub >> 2) * 32, sc = (sub & 3) * 32;
    const int it = (tt == 1) ? 1 : 0;
    const int jt = (tt == 0) ? 0 : 1;
    const bool offd = (tt == 2);
    const int gi0 = it * 128 + sr, gj0 = jt * 128 + sc;
    const int r = tid >> 3, c4 = (tid & 7) * 4;
    float gh[4] = {0.f, 0.f, 0.f, 0.f};
    for (int b = 0; b < BB; ++b) {
        float s0 = 0.f, s1 = 0.f, s2 = 0.f, s3 = 0.f;
        #pragma unroll
        for (int ks = 0; ks < 8; ++ks) {
            const float4 v = *(const float4*)&Pg[(((long)ks * 8 + b) * 3 + tt) * 16384
                                                 + (long)(sr + r) * 128 + sc + c4];
            s0 += v.x; s1 += v.y; s2 += v.z; s3 += v.w;
        }
        ushort4 w;
        w.x = f2bf(s0); w.y = f2bf(s1); w.z = f2bf(s2); w.w = f2bf(s3);
        *(ushort4*)&Gbf[(long)b * 65536 + (long)(gi0 + r) * 256 + gj0 + c4] = w;
        gh[0] += s0; gh[1] += s1; gh[2] += s2; gh[3] += s3;
        if (offd) {
            tile[r][c4 + 0] = s0; tile[r][c4 + 1] = s1;
            tile[r][c4 + 2] = s2; tile[r][c4 + 3] = s3;
            __syncthreads();
            ushort4 t;
            t.x = f2bf(tile[c4 + 0][r]); t.y = f2bf(tile[c4 + 1][r]);
            t.z = f2bf(tile[c4 + 2][r]); t.w = f2bf(tile[c4 + 3][r]);
            *(ushort4*)&Gbf[(long)b * 65536 + (long)(gj0 + r) * 256 + gi0 + c4] = t;
            __syncthreads();
        }
    }
    float4 g4;
    g4.x = gh[0] * (1.0f / PTOT); g4.y = gh[1] * (1.0f / PTOT);
    g4.z = gh[2] * (1.0f / PTOT); g4.w = gh[3] * (1.0f / PTOT);
    *(float4*)&Ghat[(long)(gi0 + r) * 256 + gj0 + c4] = g4;
    if (offd) {
        tile[r][c4 + 0] = g4.x; tile[r][c4 + 1] = g4.y;
        tile[r][c4 + 2] = g4.z; tile[r][c4 + 3] = g4.w;
        __syncthreads();
        float4 t4;
        t4.x = tile[c4 + 0][r]; t4.y = tile[c4 + 1][r];
        t4.z = tile[c4 + 2][r]; t4.w = tile[c4 + 3][r];
        *(float4*)&Ghat[(long)(gj0 + r) * 256 + gi0 + c4] = t4;
    }
}

// ---- BN stats; writes fp32 Wp (+ fp32 transposes of Wk',Wv'), bf16 mats, cvec ----
__global__ void stats_quad(const float* __restrict__ Wq, const float* __restrict__ Wk,
                           const float* __restrict__ Wv, const float* __restrict__ Ghat,
                           const float* __restrict__ xbar,
                           const float* bq, const float* gq, const float* betaq,
                           const float* bk, const float* gk, const float* betak,
                           const float* bv, const float* gv, const float* betav,
                           float* __restrict__ Wp, float* __restrict__ cvec,
                           ushort* __restrict__ WqT, ushort* __restrict__ WkT,
                           ushort* __restrict__ Wvb, float* __restrict__ WkTf,
                           float* __restrict__ WvTf) {
    const int o = blockIdx.x, t = blockIdx.y, tid = threadIdx.x;
    const float* Wt  = t == 0 ? Wq : (t == 1 ? Wk : Wv);
    const float* bt  = t == 0 ? bq : (t == 1 ? bk : bv);
    const float* gt  = t == 0 ? gq : (t == 1 ? gk : gv);
    const float* bet = t == 0 ? betaq : (t == 1 ? betak : betav);
    __shared__ float wrow[256];
    __shared__ float red[256];
    wrow[tid] = Wt[o * 256 + tid];
    __syncthreads();
    const float* grow = Ghat + (long)tid * 256;
    float tj = 0.f;
    #pragma unroll 8
    for (int k = 0; k < 256; k += 4) {
        const float4 g = *(const float4*)&grow[k];
        tj += g.x * wrow[k] + g.y * wrow[k + 1] + g.z * wrow[k + 2] + g.w * wrow[k + 3];
    }
    const float q2 = block_reduce(wrow[tid] * tj, red, tid);
    const float wx = block_reduce(wrow[tid] * xbar[tid], red, tid);
    const float bo = bt[o];
    const float mu = wx + bo;
    const float var = q2 + 2.f * bo * mu - bo * bo - mu * mu;
    const float a = gt[o] * rsqrtf(var + EPSV);
    const float wpv = a * wrow[tid];
    Wp[(long)t * 65536 + o * 256 + tid] = wpv;
    const ushort wb = f2bf(wpv);
    if (t == 0) {
        WqT[(long)tid * 256 + o] = wb;
    } else if (t == 1) {
        WkT[(long)tid * 256 + o] = wb;
        WkTf[(long)tid * 256 + o] = wpv;
    } else {
        Wvb[(long)o * 256 + tid] = wb;
        WvTf[(long)tid * 256 + o] = wpv;
    }
    if (tid == 0) cvec[t * 256 + o] = a * (bo - mu) + bet[o];
}

// ---- shared MFMA 128x128-tile GEMM body, K=256, fragments direct from L2 ----
__device__ __forceinline__ void gemm_tile(const ushort* __restrict__ Ab,
                                          const ushort* __restrict__ Bb,
                                          ushort* __restrict__ Db,
                                          int m0, int n0, int mode, int bz,
                                          const float* __restrict__ u,
                                          const float* __restrict__ cvec,
                                          const float* __restrict__ r,
                                          const float* __restrict__ hb, int tid) {
    const int wave = tid >> 6, lane = tid & 63;
    const int wr = (wave >> 1) * 64, wc = (wave & 1) * 64;
    const int m = lane & 15, q8 = (lane >> 4) * 8;
    f32x4 acc[4][4];
    #pragma unroll
    for (int a = 0; a < 4; ++a)
        #pragma unroll
        for (int q = 0; q < 4; ++q) acc[a][q] = (f32x4){0.f, 0.f, 0.f, 0.f};
    #pragma unroll
    for (int kk = 0; kk < 8; ++kk) {
        short8 af[4], bfv[4];
        #pragma unroll
        for (int a = 0; a < 4; ++a)
            af[a] = *(const short8*)&Ab[(long)(m0 + wr + a * 16 + m) * 256 + kk * 32 + q8];
        #pragma unroll
        for (int q = 0; q < 4; ++q)
            bfv[q] = *(const short8*)&Bb[(long)(n0 + wc + q * 16 + m) * 256 + kk * 32 + q8];
        #pragma unroll
        for (int a = 0; a < 4; ++a)
            #pragma unroll
            for (int q = 0; q < 4; ++q)
                acc[a][q] = MFMA16(af[a], bfv[q], acc[a][q]);
    }
    const int rq = (lane >> 4) * 4;
    #pragma unroll
    for (int a = 0; a < 4; ++a) {
        #pragma unroll
        for (int q = 0; q < 4; ++q) {
            const int col = n0 + wc + q * 16 + m;
            #pragma unroll
            for (int reg = 0; reg < 4; ++reg) {
                const int row = m0 + wr + a * 16 + rq + reg;
                const float v = acc[a][q][reg];
                if (mode == 0) {
                    Db[(long)col * 256 + row] = f2bf(v);
                } else {
                    const float rv = r[col];
                    const float t2 = hb[bz * 256 + col] + 4096.0f * rv;
                    const float val = SCALEV * (v + u[bz * 256 + row] * rv + cvec[512 + row] * t2);
                    Db[(long)row * 256 + col] = f2bf(val);
                }
            }
        }
    }
}

// ---- fused: blocks 0-3 = Z GEMM tiles; blocks 4-12 = mid_a ----
__global__ __launch_bounds__(256) void zmida(const ushort* __restrict__ WkT,
                                             const ushort* __restrict__ WqT,
                                             ushort* __restrict__ ZT,
                                             const float* __restrict__ Wp,
                                             const float* __restrict__ WkTf,
                                             const float* __restrict__ WvTf,
                                             const float* __restrict__ S,
                                             const float* __restrict__ cvec,
                                             float* __restrict__ u, float* __restrict__ w,
                                             float* __restrict__ y, float* __restrict__ r) {
    const int blk = blockIdx.x, tid = threadIdx.x;
    if (blk < 4) {
        gemm_tile(WkT, WqT, ZT, (blk >> 1) * 128, (blk & 1) * 128, 0, 0,
                  nullptr, nullptr, nullptr, nullptr, tid);
        return;
    }
    const int bidx = blk - 4;
    if (bidx < 8) {
        __shared__ float sh[256];
        sh[tid] = S[bidx * 256 + tid]; __syncthreads();
        float uu = 0.f, ww = 0.f;
        #pragma unroll 8
        for (int j = 0; j < 256; ++j) {
            uu += WvTf[(long)j * 256 + tid] * sh[j];
            ww += WkTf[(long)j * 256 + tid] * sh[j];
        }
        u[bidx * 256 + tid] = uu;
        w[bidx * 256 + tid] = ww;
    } else {
        __shared__ float cqs[256], cks[256];
        cqs[tid] = cvec[tid]; cks[tid] = cvec[256 + tid]; __syncthreads();
        float yy = 0.f, rr = 0.f;
        #pragma unroll 8
        for (int o = 0; o < 256; ++o) {
            yy += Wp[65536L + (long)o * 256 + tid] * cqs[o];
            rr += Wp[(long)o * 256 + tid] * cks[o];
        }
        y[tid] = yy;
        r[tid] = rr;
    }
}

// ---- fused: blocks 0-7 = mid_bc (reads Gbf); blocks 8-39 = F GEMM tiles ----
__global__ __launch_bounds__(256) void bcF(const float* __restrict__ Wp,
                                           const ushort* __restrict__ Gbf,
                                           const float* __restrict__ WvTf,
                                           const float* __restrict__ w,
                                           const float* __restrict__ y,
                                           const float* __restrict__ u,
                                           const float* __restrict__ cvec,
                                           float* __restrict__ hb,
                                           float* __restrict__ offv,
                                           const ushort* __restrict__ ZT,
                                           ushort* __restrict__ FT) {
    const int blk = blockIdx.x, tid = threadIdx.x;
    if (blk >= 8) {
        const int idx = blk - 8;
        const int bz = idx >> 2, t = idx & 3;
        gemm_tile(Gbf + (long)bz * 65536, ZT, FT + (long)bz * 65536,
                  (t >> 1) * 128, (t & 1) * 128, 0, 0,
                  nullptr, nullptr, nullptr, nullptr, tid);
        return;
    }
    const int b = blk;
    __shared__ float wl[256], yl[256], gyl[256], red[256], cqs[256], cks[256];
    wl[tid] = w[b * 256 + tid];
    yl[tid] = y[tid];
    cqs[tid] = cvec[tid];
    cks[tid] = cvec[256 + tid];
    const float cv = cvec[512 + tid];
    const float uu = u[b * 256 + tid];
    __syncthreads();
    float hh = 0.f, gg = 0.f;
    #pragma unroll 8
    for (int o = 0; o < 256; ++o) {
        hh += Wp[(long)o * 256 + tid] * wl[o];
        gg += bf2f(Gbf[(long)b * 65536 + (long)o * 256 + tid]) * yl[o];
    }
    hb[b * 256 + tid] = hh;
    gyl[tid] = gg;
    __syncthreads();
    float vg = 0.f;
    #pragma unroll 8
    for (int j = 0; j < 256; ++j) vg += WvTf[(long)j * 256 + tid] * gyl[j];
    const float dkq = block_reduce(cqs[tid] * cks[tid], red, tid);
    const float dwq = block_reduce(wl[tid] * cqs[tid], red, tid);
    offv[b * 256 + tid] = SCALEV * (vg + uu * dkq + cv * (dwq + 4096.0f * dkq));
}

// ---- T_b = Wv' F_b + rank-1, scaled -> Tbf. grid (2,2,8) ----
__global__ __launch_bounds__(256) void gemm_T(const ushort* __restrict__ Wvb,
                                              const ushort* __restrict__ FT,
                                              ushort* __restrict__ Tbf,
                                              const float* __restrict__ u,
                                              const float* __restrict__ cvec,
                                              const float* __restrict__ r,
                                              const float* __restrict__ hb) {
    const int bz = blockIdx.z;
    gemm_tile(Wvb, FT + (long)bz * 65536, Tbf + (long)bz * 65536,
              blockIdx.y * 128, blockIdx.x * 128, 1, bz, u, cvec, r, hb, threadIdx.x);
}

// ---- out_b = T_b x_b + off_b via MFMA; 64-pixel tiles; grid (64, 8) ----
__global__ __launch_bounds__(256) void out_mfma(const ushort* __restrict__ Tbf,
                                                const float* __restrict__ x,
                                                const float* __restrict__ offv,
                                                float* __restrict__ out) {
    __shared__ __align__(16) ushort Bs[64 * 264];
    const int tid = threadIdx.x;
    const int p0 = blockIdx.x * 64;
    const int b = blockIdx.y;
    const float* xb = x + (long)b * CC * NPIX;
    const ushort* Tb = Tbf + (long)b * 65536;

    const int c = tid & 15, kq = tid >> 4;
    #pragma unroll
    for (int kt = 0; kt < 4; ++kt) {
        const int k4 = kt * 64 + kq * 4;
        const int p = c * 4;
        const float4 v0 = *(const float4*)&xb[(long)(k4 + 0) * NPIX + p0 + p];
        const float4 v1 = *(const float4*)&xb[(long)(k4 + 1) * NPIX + p0 + p];
        const float4 v2 = *(const float4*)&xb[(long)(k4 + 2) * NPIX + p0 + p];
        const float4 v3 = *(const float4*)&xb[(long)(k4 + 3) * NPIX + p0 + p];
        ushort2 a01, a23;
        ushort4 w;
        a01 = f2bf2(v0.x, v1.x); a23 = f2bf2(v2.x, v3.x);
        w.x = a01.x; w.y = a01.y; w.z = a23.x; w.w = a23.y;
        *(ushort4*)&Bs[(p + 0) * 264 + k4] = w;
        a01 = f2bf2(v0.y, v1.y); a23 = f2bf2(v2.y, v3.y);
        w.x = a01.x; w.y = a01.y; w.z = a23.x; w.w = a23.y;
        *(ushort4*)&Bs[(p + 1) * 264 + k4] = w;
        a01 = f2bf2(v0.z, v1.z); a23 = f2bf2(v2.z, v3.z);
        w.x = a01.x; w.y = a01.y; w.z = a23.x; w.w = a23.y;
        *(ushort4*)&Bs[(p + 2) * 264 + k4] = w;
        a01 = f2bf2(v0.w, v1.w); a23 = f2bf2(v2.w, v3.w);
        w.x = a01.x; w.y = a01.y; w.z = a23.x; w.w = a23.y;
        *(ushort4*)&Bs[(p + 3) * 264 + k4] = w;
    }
    __syncthreads();

    const int wave = tid >> 6, lane = tid & 63;
    const int wr = wave * 64;
    const int m = lane & 15, q8 = (lane >> 4) * 8;
    f32x4 acc[4][4];
    #pragma unroll
    for (int a = 0; a < 4; ++a)
        #pragma unroll
        for (int q = 0; q < 4; ++q) acc[a][q] = (f32x4){0.f, 0.f, 0.f, 0.f};

    #pragma unroll
    for (int kk = 0; kk < 8; ++kk) {
        short8 af[4], bfv[4];
        #pragma unroll
        for (int a = 0; a < 4; ++a)
            af[a] = *(const short8*)&Tb[(long)(wr + a * 16 + m) * 256 + kk * 32 + q8];
        #pragma unroll
        for (int q = 0; q < 4; ++q)
            bfv[q] = *(const short8*)&Bs[(q * 16 + m) * 264 + kk * 32 + q8];
        #pragma unroll
        for (int a = 0; a < 4; ++a)
            #pragma unroll
            for (int q = 0; q < 4; ++q)
                acc[a][q] = MFMA16(af[a], bfv[q], acc[a][q]);
    }

    const int rq = (lane >> 4) * 4;
    #pragma unroll
    for (int a = 0; a < 4; ++a) {
        #pragma unroll
        for (int reg = 0; reg < 4; ++reg) {
            const int row = wr + a * 16 + rq + reg;
            const float off_ = offv[b * CC + row];
            float* orow = &out[((long)b * CC + row) * NPIX + p0];
            #pragma unroll
            for (int q = 0; q < 4; ++q)
                orow[q * 16 + m] = acc[a][q][reg] + off_;
        }
    }
}

extern "C" void kernel_launch(void* const* d_in, const int* in_sizes, int n_in,
                              void* d_out, int out_size, void* d_ws, size_t ws_size,
                              hipStream_t stream) {
    const float* x     = (const float*)d_in[0];
    const float* Wq    = (const float*)d_in[1];
    const float* bq    = (const float*)d_in[2];
    const float* gq    = (const float*)d_in[3];
    const float* betaq = (const float*)d_in[4];
    const float* Wk    = (const float*)d_in[5];
    const float* bk    = (const float*)d_in[6];
    const float* gk    = (const float*)d_in[7];
    const float* betak = (const float*)d_in[8];
    const float* Wv    = (const float*)d_in[9];
    const float* bv    = (const float*)d_in[10];
    const float* gv    = (const float*)d_in[11];
    const float* betav = (const float*)d_in[12];
    float* ws = (float*)d_ws;

    float*  Pg   = ws + OFF_PG;
    float*  Sp   = ws + OFF_SP;
    float*  S    = ws + OFF_S;
    float*  Ghat = ws + OFF_GHAT;
    float*  Xbar = ws + OFF_XBAR;
    float*  Wp   = ws + OFF_WP;
    float*  WkTf = ws + OFF_WKTF;
    float*  WvTf = ws + OFF_WVTF;
    float*  cvec = ws + OFF_CVEC;
    float*  U    = ws + OFF_U;
    float*  W2   = ws + OFF_W2;
    float*  Hb   = ws + OFF_HB;
    float*  Y    = ws + OFF_Y;
    float*  R    = ws + OFF_R;
    float*  OffV = ws + OFF_OFFV;
    ushort* Gbf  = (ushort*)(ws + OFF_GBF);
    ushort* WqT  = (ushort*)(ws + OFF_WQT);
    ushort* WkT  = (ushort*)(ws + OFF_WKT);
    ushort* Wvb  = (ushort*)(ws + OFF_WVB);
    ushort* ZT   = (ushort*)(ws + OFF_ZT);
    ushort* FT   = (ushort*)(ws + OFF_FT);
    ushort* Tbf  = (ushort*)(ws + OFF_TBF);

    gram_mfma<<<dim3(8, 8, 3), 256, 0, stream>>>(x, Pg, Sp);
    reduce_mirror<<<49, 256, 0, stream>>>(Pg, Sp, Gbf, Ghat, S, Xbar);
    stats_quad<<<dim3(256, 3), 256, 0, stream>>>(Wq, Wk, Wv, Ghat, Xbar,
                                                 bq, gq, betaq, bk, gk, betak,
                                                 bv, gv, betav, Wp, cvec,
                                                 WqT, WkT, Wvb, WkTf, WvTf);
    zmida<<<13, 256, 0, stream>>>(WkT, WqT, ZT, Wp, WkTf, WvTf, S, cvec, U, W2, Y, R);
    bcF<<<40, 256, 0, stream>>>(Wp, Gbf, WvTf, W2, Y, U, cvec, Hb, OffV, ZT, FT);
    gemm_T<<<dim3(2, 2, 8), 256, 0, stream>>>(Wvb, FT, Tbf, U, cvec, R, Hb);
    out_mfma<<<dim3(64, 8), 256, 0, stream>>>(Tbf, x, OffV, (float*)d_out);
}